// Round 1
// 266.828 us; speedup vs baseline: 1.0018x; 1.0018x over previous
//
#include <hip/hip_runtime.h>
#include <hip/hip_bf16.h>
#include <cstdint>
#include <cstddef>

// ============================================================================
// CA3RecurrentMatrix: retrieved = query @ pinv8(A) @ A
//
// Math: with M = A^T A (C x C), retrieved = query @ h8(M),
//   h8(x) = 1 - (1 - a*x)^256 = 256*a*x - O((a*x)^2), a*x <= ~7e-7
// 2nd-order term ~9.1e-5 relative -> dropped. residual/done never triggers.
// ||A||_F^2 = trace(M) from Mb diagonal.
//
// Pipeline:
//   1. At = A^T bf16                      (LDS-tiled transpose)
//   2. P[z] = At @ At^T over K-chunk z    (split-K=4, 8-phase 256^2 gemm)
//   3. Mb = bf16(sum_z P[z])
//   4. trace -> wsf[4]
//   5. qb = bf16(query)                   (overlays P)
//   6. out = c1 * (qb @ Mb^T)             (8-phase 256^2 gemm, Mb symm)
//
// gemm8 = m201-style 8-phase schedule: 256x256 tile, BK=64, 8 waves (2Mx4N),
// 128 KiB LDS (2 buf x A/B), mfma 16x16x32, raw s_barrier + counted vmcnt.
// Per K-tile t (4 phases, phase q computes C-quadrant q over K=64 = 16 MFMA):
//   q0: ds_read A-quad0 (4xb128) + B all (8xb128, held in regs); stage A0(t+1)
//   q1: ds_read A-quad1;                                         stage A1(t+1)
//   q2: ds_read A-quad2;                                         stage B0(t+2)
//   q3: ds_read A-quad3;  stage B1(t+2); s_waitcnt vmcnt(4)
//   each phase: bar; lgkmcnt(0); setprio(1); 16 MFMA; setprio(0); bar
// Write-safety: A(t+1) overwrites A(t-1) (last read: tile t-1 q3, >=1 barrier
// before the q0 stage-issue); B(t+2) overwrites B(t) (last read: tile t q0,
// 4 barriers before the q2 stage-issue). vmcnt(4) at q3 leaves exactly the
// two B(t+2) half-tiles (4 loads/wave) in flight; everything tile t+1 needs
// is drained. Tail: guards skip stages past NT; vmcnt drops to 0 there.
// LDS swizzle (both-sides): physical 16B slot p of row r holds logical
// k-slot cl = p ^ (r&7); staging pre-swizzles the *global* source address
// (linear LDS dest, as global_load_lds requires), reads apply the same XOR.
// ============================================================================

#define K_DIM 4096
#define C_DIM 2048
#define B_DIM 8192
#define SPLITK 4
#define KCHUNK (K_DIM / SPLITK)

typedef __bf16 bf16x8 __attribute__((ext_vector_type(8)));
typedef float f32x4 __attribute__((ext_vector_type(4)));

__device__ __forceinline__ void async_load16(const void* g, void* l) {
  __builtin_amdgcn_global_load_lds(
      (const __attribute__((address_space(1))) void*)g,
      (__attribute__((address_space(3))) void*)l, 16, 0, 0);
}

// ------------------------------------------------------- transpose A ------
__global__ __launch_bounds__(256) void transpose_kernel(
    const float* __restrict__ A, __hip_bfloat16* __restrict__ At) {
  __shared__ __align__(16) __hip_bfloat16 Ts[64 * 68];
  const int t = threadIdx.x;
  const int c0 = blockIdx.x * 64;
  const int k0 = blockIdx.y * 64;
  const int c_l = t & 63;
  const int kq = t >> 6;
#pragma unroll
  for (int i = 0; i < 4; ++i) {
    int k_l = i * 16 + kq * 4;
    union { __hip_bfloat16 h[4]; uint2 u; } pk;
#pragma unroll
    for (int j = 0; j < 4; ++j)
      pk.h[j] = __float2bfloat16(A[(size_t)(k0 + k_l + j) * C_DIM + c0 + c_l]);
    *(uint2*)(Ts + c_l * 68 + k_l) = pk.u;
  }
  __syncthreads();
  const int c = t >> 2;
  const int seg = t & 3;
  const __hip_bfloat16* src = Ts + c * 68 + seg * 16;
  union { uint2 d[2]; uint4 q; } o0, o1;
  o0.d[0] = *(const uint2*)(src + 0);
  o0.d[1] = *(const uint2*)(src + 4);
  o1.d[0] = *(const uint2*)(src + 8);
  o1.d[1] = *(const uint2*)(src + 12);
  __hip_bfloat16* dst = At + (size_t)(c0 + c) * K_DIM + k0 + seg * 16;
  *(uint4*)(dst + 0) = o0.q;
  *(uint4*)(dst + 8) = o1.q;
}

// ------------------------------------------------------- query -> bf16 ----
__global__ void cvt_kernel(const float* __restrict__ x,
                           __hip_bfloat16* __restrict__ y, int n4) {
  int tid = blockIdx.x * blockDim.x + threadIdx.x;
  int stride = gridDim.x * blockDim.x;
  for (int i = tid; i < n4; i += stride) {
    float4 v = ((const float4*)x)[i];
    __hip_bfloat16 o[4] = {__float2bfloat16(v.x), __float2bfloat16(v.y),
                           __float2bfloat16(v.z), __float2bfloat16(v.w)};
    *(uint2*)(y + 4 * (size_t)i) = *(const uint2*)o;
  }
}

// ----------------------------------------------- split-K partial reduce ---
__global__ void reduce_kernel(const __hip_bfloat16* __restrict__ P,
                              __hip_bfloat16* __restrict__ Mb, int n8) {
  const size_t CC = (size_t)C_DIM * C_DIM;
  int tid = blockIdx.x * blockDim.x + threadIdx.x;
  int stride = gridDim.x * blockDim.x;
  for (int i = tid; i < n8; i += stride) {
    float acc[8] = {};
#pragma unroll
    for (int s = 0; s < SPLITK; ++s) {
      uint4 raw = *(const uint4*)(P + s * CC + (size_t)i * 8);
      const __hip_bfloat16* h = (const __hip_bfloat16*)&raw;
#pragma unroll
      for (int j = 0; j < 8; ++j) acc[j] += __bfloat162float(h[j]);
    }
    __hip_bfloat16 o[8];
#pragma unroll
    for (int j = 0; j < 8; ++j) o[j] = __float2bfloat16(acc[j]);
    *(uint4*)(Mb + (size_t)i * 8) = *(const uint4*)o;
  }
}

// --------------------------------------------- trace(M) = ||A||_F^2 ------
__global__ void trace_kernel(const __hip_bfloat16* __restrict__ Mb,
                             float* __restrict__ wsf) {
  int i = blockIdx.x * 64 + threadIdx.x;
  float v = __bfloat162float(Mb[(size_t)i * (C_DIM + 1)]);
#pragma unroll
  for (int off = 32; off; off >>= 1) v += __shfl_down(v, off);
  if (threadIdx.x == 0) atomicAdd(wsf + 4, v);
}

// ------------------------------------------------------------- gemm8 -----
// out[m][n] = sum_{k in chunk} Ab[m][k] * Bb[n][k]  (both row-major in k)
// MODE 2: fp32 out = c1 * acc.  MODE 3: bf16 partial to Bp + z*C*C.
template <int MODE>
__global__ __launch_bounds__(512, 2) void gemm8(
    const __hip_bfloat16* __restrict__ Ab, const __hip_bfloat16* __restrict__ Bb,
    int ldk, int kchunk,
    float* __restrict__ Fp, __hip_bfloat16* __restrict__ Bp,
    const float* __restrict__ ls, const float* __restrict__ wsf) {
  constexpr int BK = 64;
  __shared__ __align__(16) __hip_bfloat16 As[2][256 * BK];  // 64 KiB
  __shared__ __align__(16) __hip_bfloat16 Bs[2][256 * BK];  // 64 KiB

  const int tid = threadIdx.x;
  const int wave = tid >> 6;
  const int lane = tid & 63;
  const int tile_m = blockIdx.y * 256;
  const int tile_n = blockIdx.x * 256;
  const int kstart = blockIdx.z * kchunk;
  const int wm = (wave >> 2) * 128;   // 2 M-warps
  const int wn = (wave & 3) * 64;     // 4 N-warps
  const int NT = kchunk / BK;

  // staging: half-tile = 128 rows x 64 cols; wave w covers rows 16w..16w+15
  // (2 x 1KB chunks). Linear LDS dest; source address pre-swizzled:
  // lane = (row-in-chunk lr)<<3 | physical-slot lp; fetch logical slot lp^lr.
  const int lr = lane >> 3, lp = lane & 7, lcl = lp ^ lr;
  const __hip_bfloat16* aSrc[2][2];
  const __hip_bfloat16* bSrc[2][2];
#pragma unroll
  for (int h = 0; h < 2; ++h)
#pragma unroll
    for (int c = 0; c < 2; ++c) {
      int r = h * 128 + wave * 16 + c * 8 + lr;
      aSrc[h][c] = Ab + (size_t)(tile_m + r) * ldk + kstart + lcl * 8;
      bSrc[h][c] = Bb + (size_t)(tile_n + r) * ldk + kstart + lcl * 8;
    }

  auto stA = [&](int buf, int h, int t) {
    int rb = (h * 128 + wave * 16) * BK;
    async_load16(aSrc[h][0] + (size_t)t * BK, &As[buf][rb]);
    async_load16(aSrc[h][1] + (size_t)t * BK, &As[buf][rb + 8 * BK]);
  };
  auto stB = [&](int buf, int h, int t) {
    int rb = (h * 128 + wave * 16) * BK;
    async_load16(bSrc[h][0] + (size_t)t * BK, &Bs[buf][rb]);
    async_load16(bSrc[h][1] + (size_t)t * BK, &Bs[buf][rb + 8 * BK]);
  };

  // prologue: A(0), B(0) must land; B(1) (4 loads/wave) may stay in flight
  stA(0, 0, 0); stA(0, 1, 0);
  stB(0, 0, 0); stB(0, 1, 0);
  if (NT > 1) {
    stB(1, 0, 1); stB(1, 1, 1);
    asm volatile("s_waitcnt vmcnt(4)" ::: "memory");
  } else {
    asm volatile("s_waitcnt vmcnt(0)" ::: "memory");
  }
  __builtin_amdgcn_s_barrier();

  const int l15 = lane & 15, lg = lane >> 4, l7 = lane & 7;
  f32x4 acc[8][4] = {};

  for (int t = 0; t < NT; ++t) {
    const int buf = t & 1;
    bf16x8 breg[4][2];
#pragma unroll
    for (int q = 0; q < 4; ++q) {
      // ---- ds reads for this phase (A frag: row=wm+q*32+f*16+(l&15),
      //      k-slot cl=s*4+(l>>4), physical p=cl^(row&7), row&7==l&7) ----
      bf16x8 af[2][2];
#pragma unroll
      for (int f = 0; f < 2; ++f)
#pragma unroll
        for (int s = 0; s < 2; ++s)
          af[f][s] = *(const bf16x8*)&As[buf][(wm + q * 32 + f * 16 + l15) * BK +
                                             ((((s << 2) | lg) ^ l7) << 3)];
      if (q == 0) {
#pragma unroll
        for (int j = 0; j < 4; ++j)
#pragma unroll
          for (int s = 0; s < 2; ++s)
            breg[j][s] = *(const bf16x8*)&Bs[buf][(wn + j * 16 + l15) * BK +
                                                 ((((s << 2) | lg) ^ l7) << 3)];
      }
      // ---- stage one half-tile (see schedule in header) ----
      if (q == 0 && t + 1 < NT) stA(buf ^ 1, 0, t + 1);
      if (q == 1 && t + 1 < NT) stA(buf ^ 1, 1, t + 1);
      if (q == 2 && t + 2 < NT) stB(buf, 0, t + 2);
      if (q == 3) {
        if (t + 2 < NT) {
          stB(buf, 1, t + 2);
          asm volatile("s_waitcnt vmcnt(4)" ::: "memory");
        } else {
          asm volatile("s_waitcnt vmcnt(0)" ::: "memory");
        }
      }
      __builtin_amdgcn_s_barrier();
      asm volatile("s_waitcnt lgkmcnt(0)" ::: "memory");
      __builtin_amdgcn_s_setprio(1);
#pragma unroll
      for (int s = 0; s < 2; ++s)
#pragma unroll
        for (int f = 0; f < 2; ++f)
#pragma unroll
          for (int j = 0; j < 4; ++j)
            acc[q * 2 + f][j] = __builtin_amdgcn_mfma_f32_16x16x32_bf16(
                af[f][s], breg[j][s], acc[q * 2 + f][j], 0, 0, 0);
      __builtin_amdgcn_s_setprio(0);
      __builtin_amdgcn_s_barrier();
    }
  }

  // C/D layout (16x16): col = lane&15, row = (lane>>4)*4 + reg
  if constexpr (MODE == 2) {
    const float c1 = 256.0f * fminf(expf(ls[0]), 5e-4f) / (wsf[4] + 1e-8f);
#pragma unroll
    for (int m = 0; m < 8; ++m) {
      const int gm = tile_m + wm + m * 16 + lg * 4;
#pragma unroll
      for (int j = 0; j < 4; ++j) {
        const int gn = tile_n + wn + j * 16 + l15;
#pragma unroll
        for (int r = 0; r < 4; ++r)
          Fp[(size_t)(gm + r) * C_DIM + gn] = c1 * acc[m][j][r];
      }
    }
  } else {
    const size_t zoff = (size_t)blockIdx.z * C_DIM * C_DIM;
#pragma unroll
    for (int m = 0; m < 8; ++m) {
      const int gm = tile_m + wm + m * 16 + lg * 4;
#pragma unroll
      for (int j = 0; j < 4; ++j) {
        const int gn = tile_n + wn + j * 16 + l15;
#pragma unroll
        for (int r = 0; r < 4; ++r)
          Bp[zoff + (size_t)(gm + r) * C_DIM + gn] = __float2bfloat16(acc[m][j][r]);
      }
    }
  }
}

// ------------------------------------------------------------- launch -----
extern "C" void kernel_launch(void* const* d_in, const int* in_sizes, int n_in,
                              void* d_out, int out_size, void* d_ws, size_t ws_size,
                              hipStream_t stream) {
  const float* query = (const float*)d_in[0];
  const float* A = (const float*)d_in[1];
  const float* ls = (const float*)d_in[2];
  float* out = (float*)d_out;

  char* ws = (char*)d_ws;
  float* wsf = (float*)ws;
  size_t off = 256;
  __hip_bfloat16* At = (__hip_bfloat16*)(ws + off);
  off += (size_t)C_DIM * K_DIM * 2;  // 16 MiB
  // region2: split-K partials (4 x 8 MiB bf16 = 32 MiB), later reused for qb
  __hip_bfloat16* P = (__hip_bfloat16*)(ws + off);
  __hip_bfloat16* qb = (__hip_bfloat16*)(ws + off);
  off += (size_t)B_DIM * C_DIM * 2;  // 32 MiB
  __hip_bfloat16* Mb = (__hip_bfloat16*)(ws + off);  // 8 MiB

  hipMemsetAsync(wsf, 0, 32, stream);
  transpose_kernel<<<dim3(C_DIM / 64, K_DIM / 64), 256, 0, stream>>>(A, At);

  // P[z] = At @ At^T over K-chunk z   (split-K=4 -> 256 blocks = 1/CU)
  gemm8<3><<<dim3(C_DIM / 256, C_DIM / 256, SPLITK), 512, 0, stream>>>(
      At, At, K_DIM, KCHUNK, nullptr, P, nullptr, nullptr);
  // Mb = bf16(sum_z P[z])
  reduce_kernel<<<512, 256, 0, stream>>>(P, Mb, C_DIM * C_DIM / 8);
  // trace(M) -> wsf[4]
  trace_kernel<<<32, 64, 0, stream>>>(Mb, wsf);
  // qb = bf16(query)  (overwrites P, stream-ordered after reduce)
  cvt_kernel<<<4096, 256, 0, stream>>>(query, qb, B_DIM * C_DIM / 4);
  // out = c1 * qb @ Mb^T  (Mb symmetric; 256x256 blocks -> 256 blocks = 1/CU)
  gemm8<2><<<dim3(C_DIM / 256, B_DIM / 256), 512, 0, stream>>>(
      qb, Mb, C_DIM, C_DIM, out, nullptr, ls, wsf);
}